// Round 6
// baseline (3869.601 us; speedup 1.0000x reference)
//
#include <hip/hip_runtime.h>
#include <math.h>

#define BATCH 512
#define TSEQ  256
#define HID   512
#define G4    2048
#define DECSTEPS 42

typedef __attribute__((ext_vector_type(8))) short short8v;
typedef __attribute__((ext_vector_type(16))) float f32x16;
typedef unsigned short u16;

__device__ __forceinline__ float sigf(float x){ return 1.0f/(1.0f+expf(-x)); }
__device__ __forceinline__ float bf2f(u16 u){ unsigned v = ((unsigned)u)<<16; return __builtin_bit_cast(float, v); }
__device__ __forceinline__ u16 f2bf(float f){
    unsigned u = __builtin_bit_cast(unsigned, f);
    u += 0x7fffu + ((u>>16)&1u);           // round-to-nearest-even
    return (u16)(u>>16);
}

// Split Whh fp32 -> bf16 hi/lo planes (hi = rn(x), lo = rn(x - hi))
__global__ __launch_bounds__(256) void split_whh(const float* __restrict__ W,
                                                 u16* __restrict__ hi, u16* __restrict__ lo){
    int i = (blockIdx.x*256 + threadIdx.x)*4;
    float4 v = *(const float4*)(W+i);
    u16 h0=f2bf(v.x), h1=f2bf(v.y), h2=f2bf(v.z), h3=f2bf(v.w);
    ushort4 hv = make_ushort4(h0,h1,h2,h3);
    ushort4 lv = make_ushort4(f2bf(v.x-bf2f(h0)), f2bf(v.y-bf2f(h1)),
                              f2bf(v.z-bf2f(h2)), f2bf(v.w-bf2f(h3)));
    *(ushort4*)(hi+i)=hv; *(ushort4*)(lo+i)=lv;
}

// Persistent encoder: all 256 steps + dbase build in ONE kernel.
// Block b owns batch-tile (b&7, 64 rows) x d-tile (b>>3, 16 d).
// Per-step sync: group barrier over the 32 blocks sharing a batch-tile
// (monotonic counter, agent-scope release add / acquire load).
__global__ __launch_bounds__(512, 2) void lstm_persist(
    const u16* __restrict__ Whi, const u16* __restrict__ Wlo,   // [2048][512]
    const float* __restrict__ bih, const float* __restrict__ bhh,
    const float* __restrict__ Wih, const float* __restrict__ x,
    u16* __restrict__ h0hi, u16* __restrict__ h0lo,
    u16* __restrict__ h1hi, u16* __restrict__ h1lo,
    float* __restrict__ c, float* __restrict__ dbase,
    unsigned* __restrict__ ctr)
{
    const int tid  = threadIdx.x;
    const int lane = tid & 63;
    const int wave = tid >> 6;          // 0..7
    const int kh = wave >> 2;           // K-half
    const int rq = (wave >> 1) & 1;     // row quadrant
    const int cq = wave & 1;            // col quadrant

    const int gb = blockIdx.x & 7;      // batch-tile / barrier group (XCD-local if round-robin)
    const int dt = blockIdx.x >> 3;     // d-tile 0..31
    const int b0 = gb*64, d0 = dt*16;
    unsigned* myctr = ctr + gb*32;      // 128 B apart

    __shared__ __align__(16) char smem[65536];

    // ---- staging mapping (identical to verified R5) ----
    const int tl   = tid & 255;
    const int g    = tid >> 8;
    const int srow = tl >> 2;
    const int scb  = (tl & 3) * 32;
    const int arow = b0 + srow;
    const int wrow = (srow >> 4)*HID + d0 + (srow & 15);
    const int kb   = g*256 + (tl & 3)*16;
    const size_t aoff = (size_t)arow*HID + kb;
    const u16* pBh = Whi + (size_t)wrow*HID + kb;
    const u16* pBl = Wlo + (size_t)wrow*HID + kb;
    char* sg = smem + g*32768;
    const int swr = (srow & 7) << 4;
    const int wo0 = srow*128 + (scb ^ swr);
    const int wo1 = srow*128 + ((scb+16) ^ swr);

    // ---- MFMA fragment addressing (identical to R5) ----
    const int la   = lane & 31;
    const int hi16 = (lane >> 5) * 16;
    const int ra = rq*32 + la;
    const int rb = cq*32 + la;
    const int sa = (ra & 7) << 4;
    const int sb = (rb & 7) << 4;
    char* mb  = smem + kh*32768;
    char* fAh = mb          + ra*128;
    char* fAl = mb + 8192   + ra*128;
    char* fBh = mb + 16384  + rb*128;
    char* fBl = mb + 24576  + rb*128;
    float* Cp = (float*)smem;

    // ---- epilogue constants (hoisted) ----
    const int bl  = tid >> 3;           // 0..63
    const int eb  = b0 + bl;
    const int dl0 = (tid & 7) * 2;
    float CB[2][4], WV[2][4];
#pragma unroll
    for (int j = 0; j < 2; ++j){
        const int d = d0 + dl0 + j;
#pragma unroll
        for (int q = 0; q < 4; ++q){
            CB[j][q] = bih[q*HID + d] + bhh[q*HID + d];
            WV[j][q] = Wih[q*HID + d];
        }
    }
    float creg[2] = {0.0f, 0.0f};
    const float* xrow = x + (size_t)eb*TSEQ;

    for (int t = 0; t <= TSEQ; ++t){
        const u16* shi = (t & 1) ? h1hi : h0hi;
        const u16* slo = (t & 1) ? h1lo : h0lo;
        u16* dhi = (t & 1) ? h0hi : h1hi;
        u16* dlo = (t & 1) ? h0lo : h1lo;
        const u16* pAh = shi + aoff;
        const u16* pAl = slo + aoff;

        f32x16 acc0 = {}, acc1 = {}, acc2 = {};
        uint4 r0,r1,r2,r3,r4,r5,r6,r7;
        r0 = *(const uint4*)(pAh);   r1 = *(const uint4*)(pAh+8);
        r2 = *(const uint4*)(pAl);   r3 = *(const uint4*)(pAl+8);
        r4 = *(const uint4*)(pBh);   r5 = *(const uint4*)(pBh+8);
        r6 = *(const uint4*)(pBl);   r7 = *(const uint4*)(pBl+8);
        *(uint4*)(sg+wo0)=r0;       *(uint4*)(sg+wo1)=r1;
        *(uint4*)(sg+8192+wo0)=r2;  *(uint4*)(sg+8192+wo1)=r3;
        *(uint4*)(sg+16384+wo0)=r4; *(uint4*)(sg+16384+wo1)=r5;
        *(uint4*)(sg+24576+wo0)=r6; *(uint4*)(sg+24576+wo1)=r7;

        for (int it = 0; it < 4; ++it){
            __syncthreads();
            if (it < 3){
                const int ko = (it+1)*64;
                r0 = *(const uint4*)(pAh+ko); r1 = *(const uint4*)(pAh+ko+8);
                r2 = *(const uint4*)(pAl+ko); r3 = *(const uint4*)(pAl+ko+8);
                r4 = *(const uint4*)(pBh+ko); r5 = *(const uint4*)(pBh+ko+8);
                r6 = *(const uint4*)(pBl+ko); r7 = *(const uint4*)(pBl+ko+8);
            }
#pragma unroll
            for (int kk = 0; kk < 4; ++kk){
                const int off = kk*32 + hi16;
                short8v ah = *(short8v*)(fAh + (off ^ sa));
                short8v al = *(short8v*)(fAl + (off ^ sa));
                short8v bh = *(short8v*)(fBh + (off ^ sb));
                short8v bl2 = *(short8v*)(fBl + (off ^ sb));
                acc0 = __builtin_amdgcn_mfma_f32_32x32x16_bf16(ah, bh,  acc0, 0,0,0);
                acc1 = __builtin_amdgcn_mfma_f32_32x32x16_bf16(ah, bl2, acc1, 0,0,0);
                acc2 = __builtin_amdgcn_mfma_f32_32x32x16_bf16(al, bh,  acc2, 0,0,0);
            }
            __syncthreads();
            if (it < 3){
                *(uint4*)(sg+wo0)=r0;       *(uint4*)(sg+wo1)=r1;
                *(uint4*)(sg+8192+wo0)=r2;  *(uint4*)(sg+8192+wo1)=r3;
                *(uint4*)(sg+16384+wo0)=r4; *(uint4*)(sg+16384+wo1)=r5;
                *(uint4*)(sg+24576+wo0)=r6; *(uint4*)(sg+24576+wo1)=r7;
            }
        }

        // K-partials -> LDS f32 Cpart[kh][64][64]
        f32x16 accs;
#pragma unroll
        for (int r = 0; r < 16; ++r) accs[r] = acc0[r] + acc1[r] + acc2[r];
#pragma unroll
        for (int r = 0; r < 16; ++r){
            const int crow = (r & 3) + 8*(r >> 2) + 4*(lane >> 5);
            Cp[kh*4096 + (rq*32 + crow)*64 + cq*32 + la] = accs[r];
        }
        __syncthreads();

        if (t < TSEQ){
            const float xv = xrow[t];
#pragma unroll
            for (int j = 0; j < 2; ++j){
                const int dl = dl0 + j;
                const int d  = d0 + dl;
                const float g0 = Cp[bl*64 + dl]      + Cp[4096 + bl*64 + dl]      + CB[j][0] + xv*WV[j][0];
                const float g1 = Cp[bl*64 + 16 + dl] + Cp[4096 + bl*64 + 16 + dl] + CB[j][1] + xv*WV[j][1];
                const float g2 = Cp[bl*64 + 32 + dl] + Cp[4096 + bl*64 + 32 + dl] + CB[j][2] + xv*WV[j][2];
                const float g3 = Cp[bl*64 + 48 + dl] + Cp[4096 + bl*64 + 48 + dl] + CB[j][3] + xv*WV[j][3];
                const float cn = sigf(g1)*creg[j] + sigf(g0)*tanhf(g2);
                const float hn = sigf(g3)*tanhf(cn);
                creg[j] = cn;
                const u16 hh = f2bf(hn);
                dhi[eb*HID + d] = hh;
                dlo[eb*HID + d] = f2bf(hn - bf2f(hh));
            }
            if (t == TSEQ-1){
                c[eb*HID + d0 + dl0]     = creg[0];
                c[eb*HID + d0 + dl0 + 1] = creg[1];
            }
            // ---- group barrier (32 blocks sharing this batch-tile) ----
            __syncthreads();
            if (tid == 0){
                __hip_atomic_fetch_add(myctr, 1u, __ATOMIC_RELEASE, __HIP_MEMORY_SCOPE_AGENT);
                const unsigned tgt = 32u * (unsigned)(t + 1);
                while (__hip_atomic_load(myctr, __ATOMIC_ACQUIRE, __HIP_MEMORY_SCOPE_AGENT) < tgt)
                    __builtin_amdgcn_s_sleep(2);
            }
            __syncthreads();
        } else {
            // dbase iteration (uses final h, frozen): raw pre-activations
#pragma unroll
            for (int j = 0; j < 2; ++j){
                const int dl = dl0 + j;
                const int d  = d0 + dl;
                dbase[eb*G4 + d]         = Cp[bl*64 + dl]      + Cp[4096 + bl*64 + dl]      + CB[j][0];
                dbase[eb*G4 + HID + d]   = Cp[bl*64 + 16 + dl] + Cp[4096 + bl*64 + 16 + dl] + CB[j][1];
                dbase[eb*G4 + 2*HID + d] = Cp[bl*64 + 32 + dl] + Cp[4096 + bl*64 + 32 + dl] + CB[j][2];
                dbase[eb*G4 + 3*HID + d] = Cp[bl*64 + 48 + dl] + Cp[4096 + bl*64 + 48 + dl] + CB[j][3];
            }
        }
    }
}

// Autoregressive decoder: hidden/cell frozen, dec_base precomputed. One block per batch row.
__global__ __launch_bounds__(256) void lstm_dec(
    const u16* __restrict__ hhi, const u16* __restrict__ hlo,
    const float* __restrict__ dbase, const float* __restrict__ cell,
    const float* __restrict__ Wih, const float* __restrict__ Wout,
    const float* __restrict__ bout, float* __restrict__ out)
{
    const int b   = blockIdx.x;
    const int tid = threadIdx.x;
    __shared__ float red[8];

    const int dA = tid, dB = tid + 256;
    const float woA = Wout[dA], woB = Wout[dB];
    float hA = bf2f(hhi[b*HID + dA]) + bf2f(hlo[b*HID + dA]);
    float hB = bf2f(hhi[b*HID + dB]) + bf2f(hlo[b*HID + dB]);
    const float cA = cell[b*HID + dA], cB = cell[b*HID + dB];
    const float biA = dbase[b*G4 + dA],          biB = dbase[b*G4 + dB];
    const float bfA = dbase[b*G4 + HID + dA],    bfB = dbase[b*G4 + HID + dB];
    const float bgA = dbase[b*G4 + 2*HID + dA],  bgB = dbase[b*G4 + 2*HID + dB];
    const float boA = dbase[b*G4 + 3*HID + dA],  boB = dbase[b*G4 + 3*HID + dB];
    const float wiA = Wih[dA],          wiB = Wih[dB];
    const float wfA = Wih[HID + dA],    wfB = Wih[HID + dB];
    const float wgA = Wih[2*HID + dA],  wgB = Wih[2*HID + dB];
    const float wxA = Wih[3*HID + dA],  wxB = Wih[3*HID + dB];
    const float bo  = bout[0];

    for (int s = 0; s < DECSTEPS; ++s) {
        float p = hA * woA + hB * woB;
#pragma unroll
        for (int m = 1; m < 64; m <<= 1) p += __shfl_xor(p, m, 64);
        if ((tid & 63) == 0) red[tid >> 6] = p;
        __syncthreads();
        const float ov = red[0] + red[1] + red[2] + red[3] + bo;
        if (tid == 0) out[b * DECSTEPS + s] = ov;
        __syncthreads();

        {
            const float gi = sigf(__builtin_fmaf(ov, wiA, biA));
            const float gf = sigf(__builtin_fmaf(ov, wfA, bfA));
            const float gg = tanhf(__builtin_fmaf(ov, wgA, bgA));
            const float go = sigf(__builtin_fmaf(ov, wxA, boA));
            hA = go * tanhf(gf * cA + gi * gg);
        }
        {
            const float gi = sigf(__builtin_fmaf(ov, wiB, biB));
            const float gf = sigf(__builtin_fmaf(ov, wfB, bfB));
            const float gg = tanhf(__builtin_fmaf(ov, wgB, bgB));
            const float go = sigf(__builtin_fmaf(ov, wxB, boB));
            hB = go * tanhf(gf * cB + gi * gg);
        }
    }
}

extern "C" void kernel_launch(void* const* d_in, const int* in_sizes, int n_in,
                              void* d_out, int out_size, void* d_ws, size_t ws_size,
                              hipStream_t stream) {
    const float* x    = (const float*)d_in[0];
    const float* Wih  = (const float*)d_in[1];
    const float* Whh  = (const float*)d_in[2];
    const float* bih  = (const float*)d_in[3];
    const float* bhh  = (const float*)d_in[4];
    const float* Wout = (const float*)d_in[5];
    const float* bout = (const float*)d_in[6];
    float* out = (float*)d_out;

    char* ws = (char*)d_ws;
    float*    c     = (float*)(ws);                       // 1 MB
    float*    dbase = (float*)(ws + (1u<<20));            // 4 MB
    u16*      Whi   = (u16*)  (ws + 5u*(1u<<20));         // 2 MB
    u16*      Wlo   = (u16*)  (ws + 7u*(1u<<20));         // 2 MB
    u16*      h0hi  = (u16*)  (ws + 9u*(1u<<20));         // 512 KB
    u16*      h0lo  = (u16*)  (ws + 9u*(1u<<20) + (1u<<19));
    u16*      h1hi  = (u16*)  (ws + 10u*(1u<<20));
    u16*      h1lo  = (u16*)  (ws + 10u*(1u<<20) + (1u<<19));
    unsigned* ctr   = (unsigned*)(ws + 11u*(1u<<20));     // 8 x 128B counters

    hipMemsetAsync(ws + 9u*(1u<<20), 0, (2u<<20), stream);   // h0 hi/lo = 0
    hipMemsetAsync(ctr, 0, 4096, stream);                    // barrier counters
    split_whh<<<dim3(1024), dim3(256), 0, stream>>>(Whh, Whi, Wlo);

    lstm_persist<<<dim3(256), dim3(512), 0, stream>>>(
        Whi, Wlo, bih, bhh, Wih, x,
        h0hi, h0lo, h1hi, h1lo, c, dbase, ctr);

    lstm_dec<<<dim3(BATCH), dim3(256), 0, stream>>>(h0hi, h0lo, dbase, c, Wih, Wout, bout, out);
}

// Round 7
// 2266.122 us; speedup vs baseline: 1.7076x; 1.7076x over previous
//
#include <hip/hip_runtime.h>
#include <math.h>

#define BATCH 512
#define TSEQ  256
#define HID   512
#define G4    2048
#define DECSTEPS 42
#define CPS 65            // padded Cp row stride (floats) -> breaks 8-way bank conflict
#define CPH (64*CPS)

typedef __attribute__((ext_vector_type(8))) short short8v;
typedef __attribute__((ext_vector_type(16))) float f32x16;
typedef unsigned short u16;
typedef unsigned int u32;
typedef unsigned long long u64;

__device__ __forceinline__ float sigf(float x){ return 1.0f/(1.0f+expf(-x)); }
__device__ __forceinline__ float bf2f(u32 lo16){ return __builtin_bit_cast(float, lo16<<16); }
__device__ __forceinline__ u32 f2bf(float f){
    u32 u = __builtin_bit_cast(u32, f);
    u += 0x7fffu + ((u>>16)&1u);
    return u>>16;
}

// Pack Whh fp32 -> u32 (hi16|lo16) bf16 split plane
__global__ __launch_bounds__(256) void pack_whh(const float* __restrict__ W, u32* __restrict__ P){
    int i = (blockIdx.x*256 + threadIdx.x)*4;
    float4 v = *(const float4*)(W+i);
    u32 o[4]; float f[4] = {v.x,v.y,v.z,v.w};
#pragma unroll
    for (int j=0;j<4;++j){
        u32 hi = f2bf(f[j]);
        u32 lo = f2bf(f[j] - bf2f(hi));
        o[j] = (hi<<16) | lo;
    }
    *(uint4*)(P+i) = make_uint4(o[0],o[1],o[2],o[3]);
}

#define LOADA(hs, ck, dst) { \
    const u64* _pa = (const u64*)((hs) + aoff + (ck)*64); \
    dst[0]=__hip_atomic_load(_pa+0,__ATOMIC_RELAXED,__HIP_MEMORY_SCOPE_AGENT); \
    dst[1]=__hip_atomic_load(_pa+1,__ATOMIC_RELAXED,__HIP_MEMORY_SCOPE_AGENT); \
    dst[2]=__hip_atomic_load(_pa+2,__ATOMIC_RELAXED,__HIP_MEMORY_SCOPE_AGENT); \
    dst[3]=__hip_atomic_load(_pa+3,__ATOMIC_RELAXED,__HIP_MEMORY_SCOPE_AGENT); }

#define LOADB(ck, d0v, d1v) { \
    const uint4* _pb = (const uint4*)(wsrc + (ck)*64); \
    d0v = _pb[0]; d1v = _pb[1]; }

#define STAGE(dst, A, B0, B1) { \
    u32 p0=(u32)A[0],p1=(u32)(A[0]>>32),p2=(u32)A[1],p3=(u32)(A[1]>>32), \
        p4=(u32)A[2],p5=(u32)(A[2]>>32),p6=(u32)A[3],p7=(u32)(A[3]>>32); \
    *(uint4*)((dst)+wA)       = make_uint4((p0>>16)|(p1&0xffff0000u),(p2>>16)|(p3&0xffff0000u),(p4>>16)|(p5&0xffff0000u),(p6>>16)|(p7&0xffff0000u)); \
    *(uint4*)((dst)+8192+wA)  = make_uint4((p0&0xffffu)|(p1<<16),(p2&0xffffu)|(p3<<16),(p4&0xffffu)|(p5<<16),(p6&0xffffu)|(p7<<16)); \
    u32 q0=B0.x,q1=B0.y,q2=B0.z,q3=B0.w,q4=B1.x,q5=B1.y,q6=B1.z,q7=B1.w; \
    *(uint4*)((dst)+16384+wA) = make_uint4((q0>>16)|(q1&0xffff0000u),(q2>>16)|(q3&0xffff0000u),(q4>>16)|(q5&0xffff0000u),(q6>>16)|(q7&0xffff0000u)); \
    *(uint4*)((dst)+24576+wA) = make_uint4((q0&0xffffu)|(q1<<16),(q2&0xffffu)|(q3<<16),(q4&0xffffu)|(q5<<16),(q6&0xffffu)|(q7<<16)); }

// Persistent encoder. Block b: batch-tile (b&7) x d-tile (b>>3).
// Sync: per-batch-tile counter, RELAXED agent atomics only (no fences).
// h is a packed u32 (bf16hi|bf16lo) plane, moved exclusively via relaxed
// agent-scope atomics -> coherent at Infinity Cache, no L2 maintenance.
__global__ __launch_bounds__(512, 2) void lstm_persist(
    const u32* __restrict__ Wpk,
    const float* __restrict__ bih, const float* __restrict__ bhh,
    const float* __restrict__ Wih, const float* __restrict__ x,
    u32* __restrict__ hp0, u32* __restrict__ hp1,
    float* __restrict__ c, float* __restrict__ dbase,
    unsigned* __restrict__ ctr)
{
    const int tid  = threadIdx.x;
    const int lane = tid & 63;
    const int wave = tid >> 6;
    const int kh = wave >> 2;           // k-half within each 64-chunk
    const int rq = (wave >> 1) & 1;
    const int cq = wave & 1;

    const int gb = blockIdx.x & 7;
    const int dt = blockIdx.x >> 3;
    const int b0 = gb*64, d0 = dt*16;
    unsigned* myctr = ctr + gb*32;

    __shared__ __align__(16) char smem[65536];   // 2 x 32KB chunk buffers; Cp aliases

    // staging mapping: thread -> (row 0..63, 8 k-elems)
    const int arow = tid >> 3;
    const int kseg = (tid & 7) * 8;
    const size_t aoff = (size_t)(b0 + arow)*HID + kseg;
    const int wrow = (arow >> 4)*HID + d0 + (arow & 15);
    const u32* wsrc = Wpk + (size_t)wrow*HID + kseg;
    const int wA = arow*128 + (((tid&7)*16) ^ ((arow&7)<<4));

    // MFMA fragment addressing
    const int la   = lane & 31;
    const int hi16 = (lane >> 5) * 16;
    const int ra = rq*32 + la;
    const int rb = cq*32 + la;
    const int sa = (ra & 7) << 4;
    const int sb = (rb & 7) << 4;
    const int khb = kh*64;              // byte offset of this wave's k-half in a row
    float* Cp = (float*)smem;

    // epilogue constants
    const int bl  = tid >> 3;
    const int eb  = b0 + bl;
    const int dl0 = (tid & 7) * 2;
    float CB[2][4], WV[2][4];
#pragma unroll
    for (int j = 0; j < 2; ++j){
        const int d = d0 + dl0 + j;
#pragma unroll
        for (int q = 0; q < 4; ++q){
            CB[j][q] = bih[q*HID + d] + bhh[q*HID + d];
            WV[j][q] = Wih[q*HID + d];
        }
    }
    float creg[2] = {0.0f, 0.0f};
    const float* xrow = x + (size_t)eb*TSEQ;

    for (int t = 0; t <= TSEQ; ++t){
        const u32* hs = (t & 1) ? hp1 : hp0;
        u32*       hd = (t & 1) ? hp0 : hp1;

        f32x16 acc0 = {}, acc1 = {}, acc2 = {};
        u64 aPf[2][4];
        uint4 b0v, b1v;
        LOADA(hs, 0, aPf[0]);
        LOADB(0, b0v, b1v);
        LOADA(hs, 1, aPf[1]);
        STAGE(smem, aPf[0], b0v, b1v);

#pragma unroll
        for (int it = 0; it < 8; ++it){
            __syncthreads();
            uint4 bn0, bn1;
            if (it < 7) LOADB(it+1, bn0, bn1);
            if (it < 6) LOADA(hs, it+2, aPf[it&1]);
            char* base = smem + (it&1)*32768;
#pragma unroll
            for (int kk = 0; kk < 2; ++kk){
                const int off = khb + kk*32 + hi16;
                short8v ah = *(short8v*)(base         + ra*128 + (off ^ sa));
                short8v al = *(short8v*)(base + 8192  + ra*128 + (off ^ sa));
                short8v bh = *(short8v*)(base + 16384 + rb*128 + (off ^ sb));
                short8v bl2= *(short8v*)(base + 24576 + rb*128 + (off ^ sb));
                acc0 = __builtin_amdgcn_mfma_f32_32x32x16_bf16(ah, bh,  acc0, 0,0,0);
                acc1 = __builtin_amdgcn_mfma_f32_32x32x16_bf16(ah, bl2, acc1, 0,0,0);
                acc2 = __builtin_amdgcn_mfma_f32_32x32x16_bf16(al, bh,  acc2, 0,0,0);
            }
            if (it < 7) STAGE(smem + ((it+1)&1)*32768, aPf[(it+1)&1], bn0, bn1);
        }
        __syncthreads();                 // frag reads done before Cp overwrites buffers

        f32x16 accs;
#pragma unroll
        for (int r = 0; r < 16; ++r) accs[r] = acc0[r] + acc1[r] + acc2[r];
#pragma unroll
        for (int r = 0; r < 16; ++r){
            const int crow = (r & 3) + 8*(r >> 2) + 4*(lane >> 5);
            Cp[kh*CPH + (rq*32 + crow)*CPS + cq*32 + la] = accs[r];
        }
        __syncthreads();

        if (t < TSEQ){
            const float xv = xrow[t];
            u32 pk[2];
#pragma unroll
            for (int j = 0; j < 2; ++j){
                const int dl = dl0 + j;
                const float g0 = Cp[bl*CPS + dl]      + Cp[CPH + bl*CPS + dl]      + CB[j][0] + xv*WV[j][0];
                const float g1 = Cp[bl*CPS + 16 + dl] + Cp[CPH + bl*CPS + 16 + dl] + CB[j][1] + xv*WV[j][1];
                const float g2 = Cp[bl*CPS + 32 + dl] + Cp[CPH + bl*CPS + 32 + dl] + CB[j][2] + xv*WV[j][2];
                const float g3 = Cp[bl*CPS + 48 + dl] + Cp[CPH + bl*CPS + 48 + dl] + CB[j][3] + xv*WV[j][3];
                const float cn = sigf(g1)*creg[j] + sigf(g0)*tanhf(g2);
                const float hn = sigf(g3)*tanhf(cn);
                creg[j] = cn;
                const u32 hh = f2bf(hn);
                pk[j] = (hh<<16) | f2bf(hn - bf2f(hh));
            }
            const u64 hv = (u64)pk[0] | ((u64)pk[1] << 32);
            __hip_atomic_store((u64*)(hd + (size_t)eb*HID + d0 + dl0), hv,
                               __ATOMIC_RELAXED, __HIP_MEMORY_SCOPE_AGENT);
            if (t == TSEQ-1){
                c[eb*HID + d0 + dl0]     = creg[0];
                c[eb*HID + d0 + dl0 + 1] = creg[1];
            }
            __syncthreads();             // drains vmcnt(0): h stores IF$-visible
            if (tid == 0){
                __hip_atomic_fetch_add(myctr, 1u, __ATOMIC_RELAXED, __HIP_MEMORY_SCOPE_AGENT);
                const unsigned tgt = 32u * (unsigned)(t + 1);
                while (__hip_atomic_load(myctr, __ATOMIC_RELAXED, __HIP_MEMORY_SCOPE_AGENT) < tgt)
                    __builtin_amdgcn_s_sleep(1);
            }
            __syncthreads();
        } else {
#pragma unroll
            for (int j = 0; j < 2; ++j){
                const int dl = dl0 + j;
                const int d  = d0 + dl;
                dbase[eb*G4 + d]         = Cp[bl*CPS + dl]      + Cp[CPH + bl*CPS + dl]      + CB[j][0];
                dbase[eb*G4 + HID + d]   = Cp[bl*CPS + 16 + dl] + Cp[CPH + bl*CPS + 16 + dl] + CB[j][1];
                dbase[eb*G4 + 2*HID + d] = Cp[bl*CPS + 32 + dl] + Cp[CPH + bl*CPS + 32 + dl] + CB[j][2];
                dbase[eb*G4 + 3*HID + d] = Cp[bl*CPS + 48 + dl] + Cp[CPH + bl*CPS + 48 + dl] + CB[j][3];
            }
        }
    }
}

// Decoder: hidden/cell frozen, dec_base precomputed. One block per batch row.
__global__ __launch_bounds__(256) void lstm_dec(
    const u32* __restrict__ hp,
    const float* __restrict__ dbase, const float* __restrict__ cell,
    const float* __restrict__ Wih, const float* __restrict__ Wout,
    const float* __restrict__ bout, float* __restrict__ out)
{
    const int b   = blockIdx.x;
    const int tid = threadIdx.x;
    __shared__ float red[8];

    const int dA = tid, dB = tid + 256;
    const float woA = Wout[dA], woB = Wout[dB];
    const u32 pA = hp[b*HID + dA], pB = hp[b*HID + dB];
    float hA = bf2f(pA>>16) + bf2f(pA & 0xffffu);
    float hB = bf2f(pB>>16) + bf2f(pB & 0xffffu);
    const float cA = cell[b*HID + dA], cB = cell[b*HID + dB];
    const float biA = dbase[b*G4 + dA],          biB = dbase[b*G4 + dB];
    const float bfA = dbase[b*G4 + HID + dA],    bfB = dbase[b*G4 + HID + dB];
    const float bgA = dbase[b*G4 + 2*HID + dA],  bgB = dbase[b*G4 + 2*HID + dB];
    const float boA = dbase[b*G4 + 3*HID + dA],  boB = dbase[b*G4 + 3*HID + dB];
    const float wiA = Wih[dA],          wiB = Wih[dB];
    const float wfA = Wih[HID + dA],    wfB = Wih[HID + dB];
    const float wgA = Wih[2*HID + dA],  wgB = Wih[2*HID + dB];
    const float wxA = Wih[3*HID + dA],  wxB = Wih[3*HID + dB];
    const float bo  = bout[0];

    for (int s = 0; s < DECSTEPS; ++s) {
        float p = hA * woA + hB * woB;
#pragma unroll
        for (int m = 1; m < 64; m <<= 1) p += __shfl_xor(p, m, 64);
        if ((tid & 63) == 0) red[tid >> 6] = p;
        __syncthreads();
        const float ov = red[0] + red[1] + red[2] + red[3] + bo;
        if (tid == 0) out[b * DECSTEPS + s] = ov;
        __syncthreads();

        {
            const float gi = sigf(__builtin_fmaf(ov, wiA, biA));
            const float gf = sigf(__builtin_fmaf(ov, wfA, bfA));
            const float gg = tanhf(__builtin_fmaf(ov, wgA, bgA));
            const float go = sigf(__builtin_fmaf(ov, wxA, boA));
            hA = go * tanhf(gf * cA + gi * gg);
        }
        {
            const float gi = sigf(__builtin_fmaf(ov, wiB, biB));
            const float gf = sigf(__builtin_fmaf(ov, wfB, bfB));
            const float gg = tanhf(__builtin_fmaf(ov, wgB, bgB));
            const float go = sigf(__builtin_fmaf(ov, wxB, boB));
            hB = go * tanhf(gf * cB + gi * gg);
        }
    }
}

extern "C" void kernel_launch(void* const* d_in, const int* in_sizes, int n_in,
                              void* d_out, int out_size, void* d_ws, size_t ws_size,
                              hipStream_t stream) {
    const float* x    = (const float*)d_in[0];
    const float* Wih  = (const float*)d_in[1];
    const float* Whh  = (const float*)d_in[2];
    const float* bih  = (const float*)d_in[3];
    const float* bhh  = (const float*)d_in[4];
    const float* Wout = (const float*)d_in[5];
    const float* bout = (const float*)d_in[6];
    float* out = (float*)d_out;

    char* ws = (char*)d_ws;
    float*    c     = (float*)(ws);                    // 1 MB
    float*    dbase = (float*)(ws + (1u<<20));         // 4 MB
    u32*      Wpk   = (u32*)  (ws + 5u*(1u<<20));      // 4 MB
    u32*      hp0   = (u32*)  (ws + 9u*(1u<<20));      // 1 MB
    u32*      hp1   = (u32*)  (ws + 10u*(1u<<20));     // 1 MB
    unsigned* ctr   = (unsigned*)(ws + 11u*(1u<<20));  // counters

    hipMemsetAsync(hp0, 0, (1u<<20), stream);
    hipMemsetAsync(ctr, 0, 4096, stream);
    pack_whh<<<dim3(1024), dim3(256), 0, stream>>>(Whh, Wpk);

    lstm_persist<<<dim3(256), dim3(512), 0, stream>>>(
        Wpk, bih, bhh, Wih, x, hp0, hp1, c, dbase, ctr);

    lstm_dec<<<dim3(BATCH), dim3(256), 0, stream>>>(hp0, dbase, c, Wih, Wout, bout, out);
}

// Round 8
// 1490.352 us; speedup vs baseline: 2.5964x; 1.5205x over previous
//
#include <hip/hip_runtime.h>
#include <math.h>

#define BATCH 512
#define TSEQ  256
#define HID   512
#define G4    2048
#define DECSTEPS 42
#define CPS   65
#define CPH   (64*CPS)

typedef __attribute__((ext_vector_type(8))) _Float16 half8;
typedef __attribute__((ext_vector_type(16))) float f32x16;
typedef unsigned short u16;
typedef unsigned int u32;
typedef unsigned long long u64;

__device__ __forceinline__ float sigf(float x){ return 1.0f/(1.0f+expf(-x)); }

// Whh fp32 -> fp16 plane
__global__ __launch_bounds__(256) void pack_w(const float* __restrict__ W, u16* __restrict__ P){
    int i = (blockIdx.x*256 + threadIdx.x)*4;
    float4 v = *(const float4*)(W+i);
    ushort4 o;
    o.x = __builtin_bit_cast(u16, (_Float16)v.x);
    o.y = __builtin_bit_cast(u16, (_Float16)v.y);
    o.z = __builtin_bit_cast(u16, (_Float16)v.z);
    o.w = __builtin_bit_cast(u16, (_Float16)v.w);
    *(ushort4*)(P+i) = o;
}

// Persistent encoder, fp16 single-plane MFMA, W LDS-resident.
// Block b: batch-tile (b&7) x d-tile (b>>3). Sync: per-block slots,
// relaxed agent atomics; __syncthreads drain orders h-stores before arrive.
__global__ __launch_bounds__(512, 2) void lstm_persist(
    const u16* __restrict__ Wh,           // [2048][512] fp16
    const float* __restrict__ bih, const float* __restrict__ bhh,
    const float* __restrict__ Wih, const float* __restrict__ x,
    u16* __restrict__ hp0, u16* __restrict__ hp1,   // [512][512] fp16
    float* __restrict__ c, float* __restrict__ dbase,
    u32* __restrict__ ctr)
{
    const int tid  = threadIdx.x;
    const int lane = tid & 63;
    const int wave = tid >> 6;
    const int kh = wave >> 2;           // K-half
    const int rq = (wave >> 1) & 1;     // row quadrant
    const int cq = wave & 1;            // col quadrant

    const int gb = blockIdx.x & 7;
    const int dt = blockIdx.x >> 3;
    const int b0 = gb*64, d0 = dt*16;
    u32* slots  = ctr + (size_t)gb*32*16;   // 32 slots x 64B
    u32* myslot = slots + dt*16;

    __shared__ __align__(16) char smem[98816];
    // [0,65536): W resident [64 rows][512 k] fp16 swizzled
    // [65536,98304): A dbuf 2 x [64 rows][128 k] fp16 swizzled
    // [65536,98816): Cp alias [2][64][65] f32 after K-loop

    // ---- W resident staging (once) ----
    {
        const int srow = tid >> 3;
        const int wrow = (srow >> 4)*HID + d0 + (srow & 15);
        const u16* wsrc = Wh + (size_t)wrow*HID + (tid & 7)*8;
        const int swrW  = (srow & 7) << 4;
        char* wdst = smem + srow*1024;
#pragma unroll
        for (int cc = 0; cc < 8; ++cc){
            uint4 v = *(const uint4*)(wsrc + cc*64);
            *(uint4*)(wdst + ((cc*128 + (tid&7)*16) ^ swrW)) = v;
        }
    }

    // ---- A staging mapping: thread -> (row 0..63, 16 k = 32B per chunk) ----
    const int arow = tid >> 3;
    const int swr  = (arow & 7) << 4;
    const size_t aoff = (size_t)(b0 + arow)*HID + (tid & 7)*16;
    char* ab0 = smem + 65536;
    char* ab1 = smem + 65536 + 16384;
    const int wo0 = arow*256 + (((tid&7)*32)      ^ swr);
    const int wo1 = arow*256 + (((tid&7)*32 + 16) ^ swr);

    // ---- MFMA fragment addressing (32x32x16: row=lane&31, k=(lane>>5)*8+e) ----
    const int la   = lane & 31;
    const int hi16 = (lane >> 5) * 16;
    const int ra = rq*32 + la;
    const int rb = cq*32 + la;
    const int sa = (ra & 7) << 4;
    const int sb = (rb & 7) << 4;
    char* arb = smem + 65536 + ra*256;      // + (it&1)*16384
    char* wrb = smem + rb*1024;             // + it*256
    float* Cp = (float*)(smem + 65536);

    // ---- epilogue constants ----
    const int bl  = tid >> 3;
    const int eb  = b0 + bl;
    const int dl0 = (tid & 7) * 2;
    float CB[2][4], WV[2][4];
#pragma unroll
    for (int j = 0; j < 2; ++j){
        const int d = d0 + dl0 + j;
#pragma unroll
        for (int q = 0; q < 4; ++q){
            CB[j][q] = bih[q*HID + d] + bhh[q*HID + d];
            WV[j][q] = Wih[q*HID + d];
        }
    }
    float creg[2] = {0.f, 0.f};
    const float* xrow = x + (size_t)eb*TSEQ;

#define LOADA(hs, ck, dst) { \
    const u64* _p = (const u64*)((hs) + aoff + (ck)*128); \
    dst[0]=__hip_atomic_load(_p+0,__ATOMIC_RELAXED,__HIP_MEMORY_SCOPE_AGENT); \
    dst[1]=__hip_atomic_load(_p+1,__ATOMIC_RELAXED,__HIP_MEMORY_SCOPE_AGENT); \
    dst[2]=__hip_atomic_load(_p+2,__ATOMIC_RELAXED,__HIP_MEMORY_SCOPE_AGENT); \
    dst[3]=__hip_atomic_load(_p+3,__ATOMIC_RELAXED,__HIP_MEMORY_SCOPE_AGENT); }
#define STAGEA(buf, src) { \
    *(uint4*)((buf)+wo0) = make_uint4((u32)src[0],(u32)(src[0]>>32),(u32)src[1],(u32)(src[1]>>32)); \
    *(uint4*)((buf)+wo1) = make_uint4((u32)src[2],(u32)(src[2]>>32),(u32)src[3],(u32)(src[3]>>32)); }

    for (int t = 0; t <= TSEQ; ++t){
        // ---- wait: h(t) producers done (slots >= t) ----
        if (tid < 64){
            const u32 tgt = (u32)t;
            u32* sl = slots + lane*16;
            for (;;){
                u32 v = (lane < 32) ? __hip_atomic_load(sl, __ATOMIC_RELAXED, __HIP_MEMORY_SCOPE_AGENT) : tgt;
                if (__all((int)(v >= tgt))) break;
                __builtin_amdgcn_s_sleep(1);
            }
        }
        __syncthreads();   // releases block; also orders Wres staging (t=0) / Cp reads (t>0)

        const u16* hs = (t & 1) ? hp1 : hp0;
        u16*       hd = (t & 1) ? hp0 : hp1;

        f32x16 acc = {};
        u64 ar[2][4];
        LOADA(hs, 0, ar[0]);
        LOADA(hs, 1, ar[1]);
        STAGEA(ab0, ar[0]);

#pragma unroll
        for (int it = 0; it < 4; ++it){
            __syncthreads();
            if (it < 2) LOADA(hs, it+2, ar[it&1]);
            char* abase = arb + (it&1)*16384;
            char* wbase = wrb + it*256;
#pragma unroll
            for (int kk = 0; kk < 4; ++kk){
                const int off = kh*128 + kk*32 + hi16;
                half8 av = *(half8*)(abase + (off ^ sa));
                half8 wv = *(half8*)(wbase + (off ^ sb));
                acc = __builtin_amdgcn_mfma_f32_32x32x16_f16(av, wv, acc, 0,0,0);
            }
            if (it < 3) STAGEA(((it&1) ? ab0 : ab1), ar[(it+1)&1]);
        }
        __syncthreads();   // frag reads done; Cp may overwrite A buffers

        // ---- K-partials -> Cp[kh][64][65] ----
#pragma unroll
        for (int r = 0; r < 16; ++r){
            const int crow = (r & 3) + 8*(r >> 2) + 4*(lane >> 5);
            Cp[kh*CPH + (rq*32 + crow)*CPS + cq*32 + la] = acc[r];
        }
        __syncthreads();

        if (t < TSEQ){
            const float xv = xrow[t];
            u16 hbits[2];
#pragma unroll
            for (int j = 0; j < 2; ++j){
                const int dl = dl0 + j;
                const float g0 = Cp[bl*CPS + dl]      + Cp[CPH + bl*CPS + dl]      + CB[j][0] + xv*WV[j][0];
                const float g1 = Cp[bl*CPS + 16 + dl] + Cp[CPH + bl*CPS + 16 + dl] + CB[j][1] + xv*WV[j][1];
                const float g2 = Cp[bl*CPS + 32 + dl] + Cp[CPH + bl*CPS + 32 + dl] + CB[j][2] + xv*WV[j][2];
                const float g3 = Cp[bl*CPS + 48 + dl] + Cp[CPH + bl*CPS + 48 + dl] + CB[j][3] + xv*WV[j][3];
                const float cn = sigf(g1)*creg[j] + sigf(g0)*tanhf(g2);
                const float hn = sigf(g3)*tanhf(cn);
                creg[j] = cn;
                hbits[j] = __builtin_bit_cast(u16, (_Float16)hn);
            }
            const u32 pk = (u32)hbits[0] | ((u32)hbits[1] << 16);
            __hip_atomic_store((u32*)(hd + (size_t)eb*HID + d0 + dl0), pk,
                               __ATOMIC_RELAXED, __HIP_MEMORY_SCOPE_AGENT);
            if (t == TSEQ-1){
                c[eb*HID + d0 + dl0]     = creg[0];
                c[eb*HID + d0 + dl0 + 1] = creg[1];
            }
            __syncthreads();   // drain: h stores visible, Cp reads done
            if (tid == 0)
                __hip_atomic_store(myslot, (u32)(t+1), __ATOMIC_RELAXED, __HIP_MEMORY_SCOPE_AGENT);
        } else {
#pragma unroll
            for (int j = 0; j < 2; ++j){
                const int dl = dl0 + j;
                const int d  = d0 + dl;
                dbase[eb*G4 + d]         = Cp[bl*CPS + dl]      + Cp[CPH + bl*CPS + dl]      + CB[j][0];
                dbase[eb*G4 + HID + d]   = Cp[bl*CPS + 16 + dl] + Cp[CPH + bl*CPS + 16 + dl] + CB[j][1];
                dbase[eb*G4 + 2*HID + d] = Cp[bl*CPS + 32 + dl] + Cp[CPH + bl*CPS + 32 + dl] + CB[j][2];
                dbase[eb*G4 + 3*HID + d] = Cp[bl*CPS + 48 + dl] + Cp[CPH + bl*CPS + 48 + dl] + CB[j][3];
            }
        }
    }
#undef LOADA
#undef STAGEA
}

// Decoder: hidden/cell frozen, dec_base precomputed. One block per batch row.
__global__ __launch_bounds__(256) void lstm_dec(
    const u16* __restrict__ hp, const float* __restrict__ dbase,
    const float* __restrict__ cell, const float* __restrict__ Wih,
    const float* __restrict__ Wout, const float* __restrict__ bout,
    float* __restrict__ out)
{
    const int b   = blockIdx.x;
    const int tid = threadIdx.x;
    __shared__ float red[8];

    const int dA = tid, dB = tid + 256;
    const float woA = Wout[dA], woB = Wout[dB];
    float hA = (float)__builtin_bit_cast(_Float16, hp[b*HID + dA]);
    float hB = (float)__builtin_bit_cast(_Float16, hp[b*HID + dB]);
    const float cA = cell[b*HID + dA], cB = cell[b*HID + dB];
    const float biA = dbase[b*G4 + dA],          biB = dbase[b*G4 + dB];
    const float bfA = dbase[b*G4 + HID + dA],    bfB = dbase[b*G4 + HID + dB];
    const float bgA = dbase[b*G4 + 2*HID + dA],  bgB = dbase[b*G4 + 2*HID + dB];
    const float boA = dbase[b*G4 + 3*HID + dA],  boB = dbase[b*G4 + 3*HID + dB];
    const float wiA = Wih[dA],          wiB = Wih[dB];
    const float wfA = Wih[HID + dA],    wfB = Wih[HID + dB];
    const float wgA = Wih[2*HID + dA],  wgB = Wih[2*HID + dB];
    const float wxA = Wih[3*HID + dA],  wxB = Wih[3*HID + dB];
    const float bo  = bout[0];

    for (int s = 0; s < DECSTEPS; ++s) {
        float p = hA * woA + hB * woB;
#pragma unroll
        for (int m = 1; m < 64; m <<= 1) p += __shfl_xor(p, m, 64);
        if ((tid & 63) == 0) red[tid >> 6] = p;
        __syncthreads();
        const float ov = red[0] + red[1] + red[2] + red[3] + bo;
        if (tid == 0) out[b * DECSTEPS + s] = ov;
        __syncthreads();

        {
            const float gi = sigf(__builtin_fmaf(ov, wiA, biA));
            const float gf = sigf(__builtin_fmaf(ov, wfA, bfA));
            const float gg = tanhf(__builtin_fmaf(ov, wgA, bgA));
            const float go = sigf(__builtin_fmaf(ov, wxA, boA));
            hA = go * tanhf(gf * cA + gi * gg);
        }
        {
            const float gi = sigf(__builtin_fmaf(ov, wiB, biB));
            const float gf = sigf(__builtin_fmaf(ov, wfB, bfB));
            const float gg = tanhf(__builtin_fmaf(ov, wgB, bgB));
            const float go = sigf(__builtin_fmaf(ov, wxB, boB));
            hB = go * tanhf(gf * cB + gi * gg);
        }
    }
}

extern "C" void kernel_launch(void* const* d_in, const int* in_sizes, int n_in,
                              void* d_out, int out_size, void* d_ws, size_t ws_size,
                              hipStream_t stream) {
    const float* x    = (const float*)d_in[0];
    const float* Wih  = (const float*)d_in[1];
    const float* Whh  = (const float*)d_in[2];
    const float* bih  = (const float*)d_in[3];
    const float* bhh  = (const float*)d_in[4];
    const float* Wout = (const float*)d_in[5];
    const float* bout = (const float*)d_in[6];
    float* out = (float*)d_out;

    char* ws = (char*)d_ws;
    float* c     = (float*)(ws);                    // 1 MB
    float* dbase = (float*)(ws + (1u<<20));         // 4 MB
    u16*   Wh    = (u16*)  (ws + 5u*(1u<<20));      // 2 MB fp16 plane
    u16*   hp0   = (u16*)  (ws + 7u*(1u<<20));      // 512 KB
    u16*   hp1   = (u16*)  (ws + 7u*(1u<<20) + (1u<<19));
    u32*   ctr   = (u32*)  (ws + 8u*(1u<<20));      // 8 groups x 32 slots x 64B

    hipMemsetAsync(hp0, 0, (1u<<19), stream);       // h(0) = 0
    hipMemsetAsync(ctr, 0, 16384, stream);
    pack_w<<<dim3(1024), dim3(256), 0, stream>>>(Whh, Wh);

    lstm_persist<<<dim3(256), dim3(512), 0, stream>>>(
        Wh, bih, bhh, Wih, x, hp0, hp1, c, dbase, ctr);

    lstm_dec<<<dim3(BATCH), dim3(256), 0, stream>>>(hp0, dbase, c, Wih, Wout, bout, out);
}